// Round 9
// baseline (1141.831 us; speedup 1.0000x reference)
//
#include <hip/hip_runtime.h>
#include <hip/hip_bf16.h>

// AWQ w4a16 GEMM + fused LoRA, MI355X (gfx950).
//   Xe  [8192][4160] bf16 = [ x (bf16) | t = x @ lora_a (bf16) ]
//   Wt  [11008][4160] bf16 = [ ((q - z) * s)^T | lora_b^T ]
//   out [8192][11008] f32 = Xe @ Wt^T     (K' = 4160, NT = 65 K-tiles of 64)
// GEMM r9: 128x128 tile, BK=64, 4 waves (2Mx2N, wave 64x64), 32x32x16 MFMA,
// LDS 64 KiB -> TWO independent blocks per CU (~150 regs/wave). Cross-block
// overlap hides the per-tile vmcnt(0)+barrier drain (m114 mechanism), so the
// loop is the simple proven 2-phase: stage(t+1) -> ds_read(t) -> lgkm0 ->
// MFMA -> vmcnt0 -> barrier. Swizzle sigma(row)=(row&7)^((row>>3)&3) both
// sides (r7-verified, 0 conflicts). Grid 5504 = 8*688 exact XCD swizzle.

typedef __bf16 bf16x8 __attribute__((ext_vector_type(8)));
typedef float f32x16 __attribute__((ext_vector_type(16)));

#define GLOAD_LDS16(gp, lp)                                                    \
  __builtin_amdgcn_global_load_lds(                                            \
      (const __attribute__((address_space(1))) void*)(gp),                     \
      (__attribute__((address_space(3))) void*)(lp), 16, 0, 0)

#define SB0() __builtin_amdgcn_sched_barrier(0)
#define BAR() __builtin_amdgcn_s_barrier()

__device__ __forceinline__ unsigned short f2b(float f) {
  unsigned int u = __builtin_bit_cast(unsigned int, f);
  unsigned int r = u + 0x7fffu + ((u >> 16) & 1u);  // RTNE
  return (unsigned short)(r >> 16);
}

constexpr int M_DIM = 8192;
constexpr int K_DIM = 4096;
constexpr int N_DIM = 11008;
constexpr int R_DIM = 64;
constexpr int KP = K_DIM + R_DIM;  // 4160
constexpr int NT = KP / 64;        // 65 K-tiles

// ---------------------------------------------------------------- prep: t = x@A, plus x->bf16
__global__ __launch_bounds__(256) void prep_x_kernel(
    const float* __restrict__ x, const float* __restrict__ A,
    unsigned short* __restrict__ Xe) {
  __shared__ float xs[16][128];
  __shared__ float as[128][64];
  const int tid = threadIdx.x;
  const int r0 = blockIdx.x * 16;
  const int c = tid & 63;
  const int rg = tid >> 6;
  float acc[4] = {0.f, 0.f, 0.f, 0.f};
  for (int kc = 0; kc < K_DIM; kc += 128) {
    __syncthreads();
#pragma unroll
    for (int i = 0; i < 2; ++i) {
      const int flat = i * 1024 + tid * 4;
      const int row = flat >> 7, col = flat & 127;
      const float4 v = *(const float4*)(x + (size_t)(r0 + row) * K_DIM + kc + col);
      *(float4*)&xs[row][col] = v;
      unsigned short h[4] = {f2b(v.x), f2b(v.y), f2b(v.z), f2b(v.w)};
      *(uint2*)(Xe + (size_t)(r0 + row) * KP + kc + col) = *(const uint2*)h;
    }
#pragma unroll
    for (int j = 0; j < 8; ++j)
      ((float4*)as)[j * 256 + tid] =
          ((const float4*)(A + (size_t)kc * R_DIM))[j * 256 + tid];
    __syncthreads();
    for (int kk = 0; kk < 128; kk += 4) {
      float4 xv[4];
#pragma unroll
      for (int i = 0; i < 4; ++i) xv[i] = *(const float4*)&xs[rg * 4 + i][kk];
#pragma unroll
      for (int q = 0; q < 4; ++q) {
        const float b = as[kk + q][c];
        acc[0] += ((const float*)&xv[0])[q] * b;
        acc[1] += ((const float*)&xv[1])[q] * b;
        acc[2] += ((const float*)&xv[2])[q] * b;
        acc[3] += ((const float*)&xv[3])[q] * b;
      }
    }
  }
#pragma unroll
  for (int i = 0; i < 4; ++i)
    Xe[(size_t)(r0 + rg * 4 + i) * KP + K_DIM + c] = f2b(acc[i]);
}

// ---------------------------------------------------------------- prep: dequant + transpose
__global__ __launch_bounds__(256) void dequant_kernel(
    const int* __restrict__ qw, const int* __restrict__ qz,
    const float* __restrict__ sc, unsigned short* __restrict__ Wt) {
  __shared__ unsigned short w_lds[64][257];
  const int tid = threadIdx.x;
  const int n0 = blockIdx.x * 256, k0 = blockIdx.y * 64;
  const int g = k0 >> 7;  // 64-k tile never crosses a 128-k group
  const int nl = (tid & 63) * 4;
  const int kb = tid >> 6;
  const int4 zq = *(const int4*)(qz + (size_t)g * N_DIM + n0 + nl);
  const float4 sv = *(const float4*)(sc + (size_t)g * N_DIM + n0 + nl);
#pragma unroll
  for (int i = 0; i < 16; ++i) {
    const int kl = i * 4 + kb;
    const int4 q = *(const int4*)(qw + (size_t)(k0 + kl) * N_DIM + n0 + nl);
    w_lds[kl][nl + 0] = f2b((float)(q.x - zq.x) * sv.x);
    w_lds[kl][nl + 1] = f2b((float)(q.y - zq.y) * sv.y);
    w_lds[kl][nl + 2] = f2b((float)(q.z - zq.z) * sv.z);
    w_lds[kl][nl + 3] = f2b((float)(q.w - zq.w) * sv.w);
  }
  __syncthreads();
  const int c = tid & 7;         // k-chunk (8 k = 16B)
  const int ns = (tid >> 3) & 7; // n-sub within wave
  const int w = tid >> 6;
#pragma unroll
  for (int v = 0; v < 8; ++v) {
    const int n = w * 64 + v * 8 + ns;
    unsigned short tmp[8];
#pragma unroll
    for (int i = 0; i < 8; ++i) tmp[i] = w_lds[c * 8 + i][n];
    *(uint4*)(Wt + (size_t)(n0 + n) * KP + k0 + c * 8) = *(const uint4*)tmp;
  }
}

// ---------------------------------------------------------------- prep: lora_b^T
__global__ __launch_bounds__(256) void lorab_t_kernel(
    const float* __restrict__ B, unsigned short* __restrict__ Wt) {
  __shared__ unsigned short b_lds[64][68];
  const int tid = threadIdx.x;
  const int n0 = blockIdx.x * 64;
  const int nl = tid & 63;
  const int rl0 = tid >> 6;
#pragma unroll
  for (int i = 0; i < 16; ++i) {
    const int rl = i * 4 + rl0;
    b_lds[nl][rl] = f2b(B[(size_t)rl * N_DIM + n0 + nl]);
  }
  __syncthreads();
#pragma unroll
  for (int p = 0; p < 2; ++p) {
    const int chunk = p * 256 + tid;
    const int nr = chunk >> 3, r8 = chunk & 7;
    const unsigned short* rp = &b_lds[nr][r8 * 8];
    const uint2 lo = *(const uint2*)rp;
    const uint2 hi = *(const uint2*)(rp + 4);
    uint4 v;
    v.x = lo.x; v.y = lo.y; v.z = hi.x; v.w = hi.y;
    *(uint4*)(Wt + (size_t)(n0 + nr) * KP + K_DIM + r8 * 8) = v;
  }
}

// ---------------------------------------------------------------- main GEMM (128^2, 2 blocks/CU)
__global__ __launch_bounds__(256, 2) void gemm_kernel(
    const unsigned short* __restrict__ Xe, const unsigned short* __restrict__ Wt,
    float* __restrict__ out) {
  __shared__ unsigned short lds[2][2][128 * 64];  // [buf][op A/B], 64 KiB total
  const int tid = threadIdx.x;
  const int w = tid >> 6, lane = tid & 63;
  // T1: exact XCD swizzle, 5504 = 8 * 688; bm fast within XCD for B-panel L2 reuse
  const int orig = blockIdx.x;
  const int wg = (orig & 7) * 688 + (orig >> 3);
  const int bm = wg & 63;   // 64 M-tiles
  const int bn = wg >> 6;   // 86 N-tiles
  const int wr = w >> 1, wc = w & 1;

  // staging: call i covers tile-rows i*32 + w*8 + (l>>3); lane writes phys
  // chunk l&7. sigma(row) = (row&7)^((row>>3)&3) = (l>>3)^w here, so the
  // source logical chunk = (l&7) ^ (l>>3) ^ w (pre-swizzled source, rule #21).
  const int rb = w * 8 + (lane >> 3);
  const int sc = ((lane & 7) ^ (lane >> 3) ^ w) * 8;
  const unsigned short* gA = Xe + (size_t)(bm * 128 + rb) * KP + sc;
  const unsigned short* gB = Wt + (size_t)(bn * 128 + rb) * KP + sc;

  // fragment reads: row = base + (l&31), base multiple of 32 -> sigma =
  // (l&7)^((l>>3)&3); logical chunk = 2ks+(l>>5) -> phys = logical ^ sigma.
  const int rowA32 = (wr * 64 + (lane & 31)) * 64;
  const int rowB32 = (wc * 64 + (lane & 31)) * 64;
  int cxk[4];
#pragma unroll
  for (int ks = 0; ks < 4; ++ks)
    cxk[ks] = ((ks * 2 + (lane >> 5)) ^ (lane & 7) ^ ((lane >> 3) & 3)) * 8;

  f32x16 acc[2][2];
#pragma unroll
  for (int i = 0; i < 2; ++i)
#pragma unroll
    for (int j = 0; j < 2; ++j) acc[i][j] = (f32x16)0.f;

  bf16x8 a[2][4], b[2][4];

  // one gload_lds call: 32 rows (4 waves x 8) of op region, rows [i*32, +32)
  auto stage1 = [&](const unsigned short* g, int buf, int op, int i, int kt) {
    const unsigned short* s = g + (size_t)(i * 32) * KP + kt * 64;
    unsigned short* d = &lds[buf][op][(i * 32 + w * 8) * 64];
    GLOAD_LDS16(s, d);
  };

#define STAGE(BUF, KT)                                                         \
  do {                                                                         \
    stage1(gA, BUF, 0, 0, KT); stage1(gA, BUF, 0, 1, KT);                      \
    stage1(gA, BUF, 0, 2, KT); stage1(gA, BUF, 0, 3, KT);                      \
    stage1(gB, BUF, 1, 0, KT); stage1(gB, BUF, 1, 1, KT);                      \
    stage1(gB, BUF, 1, 2, KT); stage1(gB, BUF, 1, 3, KT);                      \
  } while (0)

#define LDALL(BUF)                                                             \
  do {                                                                         \
    const unsigned short* RA = &lds[BUF][0][0];                                \
    const unsigned short* RB = &lds[BUF][1][0];                                \
    _Pragma("unroll") for (int m = 0; m < 2; ++m)                              \
    _Pragma("unroll") for (int ks = 0; ks < 4; ++ks)                           \
      a[m][ks] = *(const bf16x8*)(RA + m * 2048 + rowA32 + cxk[ks]);           \
    _Pragma("unroll") for (int n = 0; n < 2; ++n)                              \
    _Pragma("unroll") for (int ks = 0; ks < 4; ++ks)                           \
      b[n][ks] = *(const bf16x8*)(RB + n * 2048 + rowB32 + cxk[ks]);           \
  } while (0)

#define MFMALL()                                                               \
  do {                                                                         \
    _Pragma("unroll") for (int ks = 0; ks < 4; ++ks)                           \
    _Pragma("unroll") for (int m = 0; m < 2; ++m)                              \
    _Pragma("unroll") for (int n = 0; n < 2; ++n)                              \
      acc[m][n] = __builtin_amdgcn_mfma_f32_32x32x16_bf16(                     \
          a[m][ks], b[n][ks], acc[m][n], 0, 0, 0);                             \
  } while (0)

// One K-tile: stage next, read this, lgkm0, MFMA, drain stages, barrier.
// Sibling block on the CU fills the drain/barrier stall.
#define TILE(KT, BUF, S1)                                                      \
  do {                                                                         \
    if (S1) STAGE((BUF) ^ 1, (KT) + 1);                                        \
    LDALL(BUF);                                                                \
    asm volatile("s_waitcnt lgkmcnt(0)" ::: "memory");                         \
    SB0();                                                                     \
    __builtin_amdgcn_s_setprio(1);                                             \
    MFMALL();                                                                  \
    __builtin_amdgcn_s_setprio(0);                                             \
    SB0();                                                                     \
    if (S1) { asm volatile("s_waitcnt vmcnt(0)" ::: "memory"); }               \
    SB0(); BAR(); SB0();                                                       \
  } while (0)

  // prologue: tile 0 into buf0
  STAGE(0, 0);
  asm volatile("s_waitcnt vmcnt(0)" ::: "memory");
  SB0(); BAR(); SB0();

#pragma unroll 1
  for (int kt = 0; kt < 64; kt += 2) {
    TILE(kt, 0, true);
    TILE(kt + 1, 1, (kt + 2 < NT));
  }
  TILE(64, 0, false);

  // epilogue: 32x32 C/D layout: col = lane&31, row = (reg&3)+8*(reg>>2)+4*(lane>>5)
  const int orow = bm * 128 + wr * 64 + ((lane >> 5) << 2);
  const int ocol = bn * 128 + wc * 64 + (lane & 31);
#pragma unroll
  for (int mf = 0; mf < 2; ++mf)
#pragma unroll
    for (int nf = 0; nf < 2; ++nf)
#pragma unroll
      for (int reg = 0; reg < 16; ++reg)
        out[(size_t)(orow + mf * 32 + (reg & 3) + ((reg >> 2) << 3)) * N_DIM +
            ocol + nf * 32] = acc[mf][nf][reg];
}

// ---------------------------------------------------------------- launch
extern "C" void kernel_launch(void* const* d_in, const int* in_sizes, int n_in,
                              void* d_out, int out_size, void* d_ws, size_t ws_size,
                              hipStream_t stream) {
  const float* x = (const float*)d_in[0];
  const float* scales = (const float*)d_in[1];
  const float* lora_a = (const float*)d_in[2];
  const float* lora_b = (const float*)d_in[3];
  const int* qweight = (const int*)d_in[4];
  const int* qzeros = (const int*)d_in[5];
  float* out = (float*)d_out;

  unsigned short* Xe = (unsigned short*)d_ws;
  unsigned short* Wt = Xe + (size_t)M_DIM * KP;

  prep_x_kernel<<<M_DIM / 16, 256, 0, stream>>>(x, lora_a, Xe);
  dequant_kernel<<<dim3(N_DIM / 256, K_DIM / 64), 256, 0, stream>>>(qweight, qzeros,
                                                                    scales, Wt);
  lorab_t_kernel<<<N_DIM / 64, 256, 0, stream>>>(lora_b, Wt);
  gemm_kernel<<<dim3((N_DIM / 128) * (M_DIM / 128)), 256, 0, stream>>>(Xe, Wt, out);
}